// Round 13
// baseline (201.919 us; speedup 1.0000x reference)
//
#include <hip/hip_runtime.h>

// MultiHeadSelfAttention: B=4, N=2048, D=1024, H=16, Hd=64
// QKV GEMM: 256x256 8-phase, CORRECTED stagger: stage-units = per-phase row
// sets, 4-7 phase lookahead, uniform vmcnt(8) waits, XCD-affinity order.
// Attention: R11 kernel. Proj: 128^2 2-phase.

typedef __attribute__((ext_vector_type(8))) short bf16x8;
typedef __attribute__((ext_vector_type(4))) short s16x4;
typedef __attribute__((ext_vector_type(4))) float f32x4;
typedef __attribute__((ext_vector_type(16))) float f32x16;
typedef __attribute__((ext_vector_type(4))) unsigned u32x4;

#define LOG2E 1.44269504088896340736f

__device__ static inline short f2bf(float f) {
  unsigned u = __builtin_bit_cast(unsigned, f);
  unsigned r = (u + 0x7fffu + ((u >> 16) & 1u)) >> 16;
  return (short)r;
}
__device__ static inline unsigned cvtpk_bf16(float lo, float hi) {
  unsigned r;
  asm("v_cvt_pk_bf16_f32 %0, %1, %2" : "=v"(r) : "v"(lo), "v"(hi));
  return r;
}
__device__ static inline float exp2_hw(float x) {
#if __has_builtin(__builtin_amdgcn_exp2f)
  return __builtin_amdgcn_exp2f(x);
#else
  float r;
  asm("v_exp_f32 %0, %1" : "=v"(r) : "v"(x));
  return r;
#endif
}

__device__ static inline void gload_lds16(const void* g, void* l) {
  __builtin_amdgcn_global_load_lds(
      (const __attribute__((address_space(1))) void*)g,
      (__attribute__((address_space(3))) void*)l, 16, 0, 0);
}

// ---------------- fp32 -> bf16 convert ----------------
__global__ void cvt_f32_bf16(const float* __restrict__ in, short* __restrict__ out, int n4) {
  int i = blockIdx.x * 256 + threadIdx.x;
  if (i < n4) {
    float4 v = ((const float4*)in)[i];
    s16x4 o4 = { f2bf(v.x), f2bf(v.y), f2bf(v.z), f2bf(v.w) };
    ((s16x4*)out)[i] = o4;
  }
}

// ---------------- QKV GEMM: 256x256 tile, BK=64, 8-phase (fixed) ----------------
// Grid: 384 linear; xcd=id&7 owns bm in [xcd*4, xcd*4+4), bn fast inner.
// LDS: buf b at b*65536: A [256][64] (+0), B (+32768). Row 128B, chunk slot =
// chunk ^ (row&7). 8 waves = 2M x 4N; wave out 128x64. Phase (MH,NH) = one
// 64x32 C-chunk x K=64: 16 MFMA; A-frags read at NH=0, held for NH=1.
__global__ __launch_bounds__(512, 2) void gemm_qkv(
    const short* __restrict__ A, const short* __restrict__ Bm,
    const float* __restrict__ bias,
    short* __restrict__ qo, short* __restrict__ ko, short* __restrict__ vto) {
  __shared__ __align__(16) char smem[131072];
  const int tid = threadIdx.x, lane = tid & 63, w = tid >> 6;
  const int wm = w >> 2, wn = w & 3;
  const int id = blockIdx.x;
  const int s = id >> 3;
  const int bm = (id & 7) * 4 + (s & 3);   // XCD owns 4 contiguous bm
  const int bn = s >> 2;
  const int fr = lane & 15;
  const int cb0 = ((((lane >> 4))       ^ (lane & 7)) << 4);
  const int cb1 = (((((lane >> 4)) + 4) ^ (lane & 7)) << 4);

  char* ldsA0 = smem;
  char* ldsB0 = smem + 32768;
  char* ldsA1 = smem + 65536;
  char* ldsB1 = smem + 98304;

  const short* Ag = A + (size_t)(bm * 256) * 1024;
  const short* Bg = Bm + (size_t)(bn * 256) * 1024;

  // A-half h: storage rows {h*64..h*64+63} U {128+h*64..}; 16KB, 2 gload/thr.
  auto STAGE_A = [&](const short* __restrict__ mg, int kt, int h, char* lds) {
#pragma unroll
    for (int sw = 0; sw < 2; ++sw) {
      int seg = w * 2 + sw;  // 0..15, wave-uniform
      int base = (seg < 8) ? (h * 64 + seg * 8) : (128 + h * 64 + (seg - 8) * 8);
      gload_lds16(mg + (size_t)(base + (lane >> 3)) * 1024 + (kt & 15) * 64 +
                      ((lane & 7) ^ (lane >> 3)) * 8,
                  lds + base * 128);
    }
  };
  // B-half h: rows wn*64 + h*32 + 0..31 for wn 0..3.
  auto STAGE_B = [&](const short* __restrict__ mg, int kt, int h, char* lds) {
#pragma unroll
    for (int sw = 0; sw < 2; ++sw) {
      int seg = w * 2 + sw;
      int base = (seg >> 2) * 64 + h * 32 + (seg & 3) * 8;
      gload_lds16(mg + (size_t)(base + (lane >> 3)) * 1024 + (kt & 15) * 64 +
                      ((lane & 7) ^ (lane >> 3)) * 8,
                  lds + base * 128);
    }
  };

  f32x4 acc[8][4];
  const f32x4 z4 = {0.f, 0.f, 0.f, 0.f};
#pragma unroll
  for (int i = 0; i < 8; ++i)
#pragma unroll
    for (int jj = 0; jj < 4; ++jj) acc[i][jj] = z4;

  bf16x8 a[4][2], b[2][2];

  // prologue: tile0 full (8), then A1h0 (2), B1h0+A1h1 (4) -> vmcnt(6)
  STAGE_A(Ag, 0, 0, ldsA0);
  STAGE_B(Bg, 0, 0, ldsB0);
  STAGE_B(Bg, 0, 1, ldsB0);
  STAGE_A(Ag, 0, 1, ldsA0);
  STAGE_A(Ag, 1, 0, ldsA1);
  STAGE_B(Bg, 1, 0, ldsB1);
  STAGE_A(Ag, 1, 1, ldsA1);
  asm volatile("s_waitcnt vmcnt(6)" ::: "memory");
  __builtin_amdgcn_s_barrier();

#define PHASE(BUF, MH, NH, RDA, WAIT, ...)                                     \
  {                                                                            \
    const char* Ab_ = smem + (BUF) * 65536;                                    \
    const char* Bb_ = Ab_ + 32768;                                             \
    if (RDA) {                                                                 \
      _Pragma("unroll")                                                        \
      for (int mf = 0; mf < 4; ++mf) {                                         \
        const char* ar = Ab_ + (wm * 128 + (MH) * 64 + mf * 16 + fr) * 128;    \
        a[mf][0] = *(const bf16x8*)(ar + cb0);                                 \
        a[mf][1] = *(const bf16x8*)(ar + cb1);                                 \
      }                                                                        \
    }                                                                          \
    _Pragma("unroll")                                                          \
    for (int nf = 0; nf < 2; ++nf) {                                           \
      const char* br = Bb_ + (wn * 64 + (NH) * 32 + nf * 16 + fr) * 128;       \
      b[nf][0] = *(const bf16x8*)(br + cb0);                                   \
      b[nf][1] = *(const bf16x8*)(br + cb1);                                   \
    }                                                                          \
    __VA_ARGS__;                                                               \
    __builtin_amdgcn_s_barrier();                                              \
    __builtin_amdgcn_sched_barrier(0);                                         \
    __builtin_amdgcn_s_setprio(1);                                             \
    _Pragma("unroll")                                                          \
    for (int mf = 0; mf < 4; ++mf) {                                           \
      _Pragma("unroll")                                                        \
      for (int nf = 0; nf < 2; ++nf) {                                         \
        acc[(MH)*4 + mf][(NH)*2 + nf] = __builtin_amdgcn_mfma_f32_16x16x32_bf16( \
            a[mf][0], b[nf][0], acc[(MH)*4 + mf][(NH)*2 + nf], 0, 0, 0);       \
        acc[(MH)*4 + mf][(NH)*2 + nf] = __builtin_amdgcn_mfma_f32_16x16x32_bf16( \
            a[mf][1], b[nf][1], acc[(MH)*4 + mf][(NH)*2 + nf], 0, 0, 0);       \
      }                                                                        \
    }                                                                          \
    __builtin_amdgcn_s_setprio(0);                                             \
    if (WAIT) asm volatile("s_waitcnt vmcnt(8)" ::: "memory");                 \
    __builtin_amdgcn_s_barrier();                                              \
    __builtin_amdgcn_sched_barrier(0);                                         \
  }

  // Stage slots (consumer, distance): ph0:B(t+1)h1 (ph5, 5) | ph1:A(t+2)h0
  // (ph0', 7) | ph3:A(t+2)h1 (ph2', 7) + B(t+2)h0 (ph0', 5) | ph4:B(t+2)h1
  // (ph1', 5) | ph5:A(t+3)h0 (ph4', 7) | ph7:A(t+3)h1 (ph6', 7) + B(t+3)h0
  // (ph4', 5). vmcnt(8) at ph0/ph3/ph4/ph7 drains loads >=4 phases old only.
  for (int j = 0; j < 8; ++j) {
    const int t = 2 * j;
    PHASE(0, 0, 0, true,  true,  STAGE_B(Bg, t + 1, 1, ldsB1));
    PHASE(0, 0, 1, false, false, STAGE_A(Ag, t + 2, 0, ldsA0));
    PHASE(0, 1, 0, true,  false, (void)0);
    PHASE(0, 1, 1, false, true,  STAGE_A(Ag, t + 2, 1, ldsA0); STAGE_B(Bg, t + 2, 0, ldsB0));
    PHASE(1, 0, 0, true,  true,  STAGE_B(Bg, t + 2, 1, ldsB0));
    PHASE(1, 0, 1, false, false, STAGE_A(Ag, t + 3, 0, ldsA1));
    PHASE(1, 1, 0, true,  false, (void)0);
    PHASE(1, 1, 1, false, true,  STAGE_A(Ag, t + 3, 1, ldsA1); STAGE_B(Bg, t + 3, 0, ldsB1));
  }
#undef PHASE

  asm volatile("s_waitcnt vmcnt(0)" ::: "memory");

  // ---- epilogue: scatter q (scaled), k, v (bit2<->3 permuted cols) ----
  const int which = bn >> 2;                 // 0=q 1=k 2=v
  const int head = (bn & 3) * 4 + wn;
  const int batch = bm >> 3;
  const size_t bh = (size_t)batch * 16 + head;
  const int rbase = (bm & 7) * 256 + wm * 128 + ((lane >> 4) << 2);
#pragma unroll
  for (int nf16 = 0; nf16 < 4; ++nf16) {
    const int dd = nf16 * 16 + fr;
    const float bv = bias[bn * 256 + wn * 64 + dd];
#pragma unroll
    for (int mf = 0; mf < 8; ++mf) {
      const int nr0 = rbase + mf * 16;
      if (which == 2) {
        int nper = (nr0 & ~12) | ((nr0 & 4) << 1) | ((nr0 & 8) >> 1);
        s16x4 pk;
#pragma unroll
        for (int r = 0; r < 4; ++r) pk[r] = f2bf(acc[mf][nf16][r] + bv);
        *(s16x4*)(vto + (bh * 64 + dd) * 2048 + nper) = pk;
      } else if (which == 0) {
        short* dst = qo + (bh * 2048 + nr0) * 64 + dd;
#pragma unroll
        for (int r = 0; r < 4; ++r)
          dst[(size_t)r * 64] = f2bf((acc[mf][nf16][r] + bv) * (0.125f * LOG2E));
      } else {
        short* dst = ko + (bh * 2048 + nr0) * 64 + dd;
#pragma unroll
        for (int r = 0; r < 4; ++r) dst[(size_t)r * 64] = f2bf(acc[mf][nf16][r] + bv);
      }
    }
  }
}

// ---------------- proj GEMM: 128^2 2-phase (unchanged) ----------------
template <int EPI>
__global__ __launch_bounds__(256, 2) void gemm_bt(
    const short* __restrict__ A, const short* __restrict__ Bm,
    const float* __restrict__ bias, int K,
    float* __restrict__ outf) {
  __shared__ __align__(16) char smem[16384];
  char* As = smem;
  char* Bs = smem + 8192;
  const int tid = threadIdx.x, lane = tid & 63, w = tid >> 6;
  const int wm = w >> 1, wn = w & 1;
  const int bm = blockIdx.y, bn = blockIdx.x;

  f32x4 acc[4][4];
  const f32x4 z4 = {0.f, 0.f, 0.f, 0.f};
#pragma unroll
  for (int m = 0; m < 4; ++m)
#pragma unroll
    for (int n = 0; n < 4; ++n) acc[m][n] = z4;

  const short* Abase = A + (size_t)bm * 128 * K;
  const short* Bbase = Bm + (size_t)bn * 128 * K;

  for (int k0 = 0; k0 < K; k0 += 32) {
#pragma unroll
    for (int j = 0; j < 2; ++j) {
      int ia = w * 2 + j;
      int row = ia * 16 + (lane >> 2);
      int cl = (lane & 3) ^ (row & 3);
      gload_lds16(Abase + (size_t)row * K + k0 + cl * 8, As + ia * 1024);
      gload_lds16(Bbase + (size_t)row * K + k0 + cl * 8, Bs + ia * 1024);
    }
    __syncthreads();

    bf16x8 af[4], bf[4];
#pragma unroll
    for (int m = 0; m < 4; ++m) {
      int r = wm * 64 + m * 16 + (lane & 15);
      af[m] = *(const bf16x8*)(As + r * 64 + ((((lane >> 4)) ^ (r & 3)) << 4));
    }
#pragma unroll
    for (int n = 0; n < 4; ++n) {
      int r = wn * 64 + n * 16 + (lane & 15);
      bf[n] = *(const bf16x8*)(Bs + r * 64 + ((((lane >> 4)) ^ (r & 3)) << 4));
    }
#pragma unroll
    for (int m = 0; m < 4; ++m)
#pragma unroll
      for (int n = 0; n < 4; ++n)
        acc[m][n] = __builtin_amdgcn_mfma_f32_16x16x32_bf16(af[m], bf[n], acc[m][n], 0, 0, 0);
    __syncthreads();
  }

#pragma unroll
  for (int nf = 0; nf < 4; ++nf) {
    int gn = bn * 128 + wn * 64 + nf * 16 + (lane & 15);
    float bv = bias[gn];
#pragma unroll
    for (int m = 0; m < 4; ++m) {
      int gm0 = bm * 128 + wm * 64 + m * 16 + ((lane >> 4) << 2);
      float* dst = outf + (size_t)gm0 * 1024 + gn;
#pragma unroll
      for (int r = 0; r < 4; ++r) dst[(size_t)r * 1024] = acc[m][nf][r] + bv;
    }
  }
}

// two PV B-frags (K=16 each) from one exp'd s-vector (V pre-permuted)
#define BUILD_PF2(d0, d1, sv)                                                  \
  {                                                                            \
    u32x4 w0_ = {cvtpk_bf16(sv[0], sv[1]), cvtpk_bf16(sv[2], sv[3]),           \
                 cvtpk_bf16(sv[4], sv[5]), cvtpk_bf16(sv[6], sv[7])};          \
    d0 = __builtin_bit_cast(bf16x8, w0_);                                      \
    u32x4 w1_ = {cvtpk_bf16(sv[8], sv[9]), cvtpk_bf16(sv[10], sv[11]),         \
                 cvtpk_bf16(sv[12], sv[13]), cvtpk_bf16(sv[14], sv[15])};      \
    d1 = __builtin_bit_cast(bf16x8, w1_);                                      \
  }

// ---------------- flash attention (R11, unchanged) ----------------
__global__ __launch_bounds__(256, 3) void attn_kernel(
    const short* __restrict__ q, const short* __restrict__ kk,
    const short* __restrict__ vt, short* __restrict__ ao) {
  __shared__ __align__(16) char smem[32768];
  const int tid = threadIdx.x, lane = tid & 63, w = tid >> 6;
  const int r31 = lane & 31, h = lane >> 5;
  const int id = blockIdx.x;
  const int xcd = id & 7, p = id >> 3;
  const int bh = xcd * 8 + (p >> 4);
  const int qblk = p & 15;
  const int q0 = qblk * 128 + w * 32;

  const short* qptr = q + ((size_t)bh * 2048 + q0 + r31) * 64 + h * 8;
  const short* kgl = kk + (size_t)bh * 2048 * 64;
  const short* vgl = vt + (size_t)bh * 64 * 2048;

  const int srow = w * 16 + (lane >> 3);
  const int scol = ((lane & 7) * 8) ^ ((lane >> 3) << 3);
  const int ldst = w * 2048;

  bf16x8 qf[4];
#pragma unroll
  for (int dk = 0; dk < 4; ++dk) qf[dk] = *(const bf16x8*)(qptr + dk * 16);

  f32x16 o0, o1;
#pragma unroll
  for (int e = 0; e < 16; ++e) { o0[e] = 0.f; o1[e] = 0.f; }
  float ls[4];
#pragma unroll
  for (int e = 0; e < 4; ++e) ls[e] = 0.f;

#pragma unroll
  for (int j = 0; j < 2; ++j) {
    gload_lds16(kgl + (size_t)(srow + j * 8) * 64 + scol, smem + ldst + j * 1024);
    gload_lds16(vgl + (size_t)(srow + j * 8) * 2048 + scol, smem + 8192 + ldst + j * 1024);
  }
  __syncthreads();

  int cur = 0;
  for (int t = 0; t < 2048; t += 64) {
    const char* Kb = smem + cur * 16384;
    const char* Vb = smem + cur * 16384 + 8192;

    if (t + 64 < 2048) {
      char* nb = (char*)smem + (cur ^ 1) * 16384;
#pragma unroll
      for (int j = 0; j < 2; ++j) {
        gload_lds16(kgl + (size_t)(t + 64 + srow + j * 8) * 64 + scol, nb + ldst + j * 1024);
        gload_lds16(vgl + (size_t)(srow + j * 8) * 2048 + (t + 64) + scol, nb + 8192 + ldst + j * 1024);
      }
    }

    bf16x8 kf0[4], kf1[4];
#pragma unroll
    for (int dk = 0; dk < 4; ++dk) {
      int cb = (dk * 32 + h * 16) ^ ((r31 & 7) << 4);
      kf0[dk] = *(const bf16x8*)(Kb + r31 * 128 + cb);
      kf1[dk] = *(const bf16x8*)(Kb + (32 + r31) * 128 + cb);
    }

    f32x16 s0, s1;
#pragma unroll
    for (int e = 0; e < 16; ++e) { s0[e] = 0.f; s1[e] = 0.f; }
#pragma unroll
    for (int dk = 0; dk < 4; ++dk) {
      s0 = __builtin_amdgcn_mfma_f32_32x32x16_bf16(kf0[dk], qf[dk], s0, 0, 0, 0);
      s1 = __builtin_amdgcn_mfma_f32_32x32x16_bf16(kf1[dk], qf[dk], s1, 0, 0, 0);
    }

#pragma unroll
    for (int e = 0; e < 16; ++e) {
      s0[e] = exp2_hw(s0[e]);
      s1[e] = exp2_hw(s1[e]);
    }
#pragma unroll
    for (int e = 0; e < 4; ++e) {
      float t0 = (s0[e] + s0[e + 4]) + (s0[e + 8] + s0[e + 12]);
      float t1 = (s1[e] + s1[e + 4]) + (s1[e + 8] + s1[e + 12]);
      ls[e] += t0 + t1;
    }

    bf16x8 pf0, pf1, pf2, pf3;
    BUILD_PF2(pf0, pf1, s0);
    BUILD_PF2(pf2, pf3, s1);

    {
      bf16x8 v00, v10, v01, v11;
      int cb0 = (0 * 32 + h * 16) ^ ((r31 & 7) << 4);
      int cb1 = (1 * 32 + h * 16) ^ ((r31 & 7) << 4);
      v00 = *(const bf16x8*)(Vb + r31 * 128 + cb0);
      v10 = *(const bf16x8*)(Vb + (32 + r31) * 128 + cb0);
      v01 = *(const bf16x8*)(Vb + r31 * 128 + cb1);
      v11 = *(const bf16x8*)(Vb + (32 + r31) * 128 + cb1);
      o0 = __builtin_amdgcn_mfma_f32_32x32x16_bf16(v00, pf0, o0, 0, 0, 0);
      o1 = __builtin_amdgcn_mfma_f32_32x32x16_bf16(v10, pf0, o1, 0, 0, 0);
      o0 = __builtin_amdgcn_mfma_f32_32x32x16_bf16(v01, pf1, o0, 0, 0, 0);
      o1 = __builtin_amdgcn_mfma_f32_32x32x16_bf16(v11, pf1, o1, 0, 0, 0);
    }
    {
      bf16x8 v02, v12, v03, v13;
      int cb2 = (2 * 32 + h * 16) ^ ((r31 & 7) << 4);
      int cb3 = (3 * 32 + h * 16) ^ ((r31 & 7) << 4);
      v02 = *(const bf16x8*)(Vb + r31 * 128 + cb2);
      v12 = *(const bf16x8*)(Vb + (32 + r31) * 128 + cb2);
      v03 = *(const bf16x8*)(Vb + r31 * 128 + cb3);
      v13 = *(const bf16x8*)(Vb + (32 + r31) * 128 + cb3);
      o0 = __builtin_amdgcn_mfma_f32_32x32x16_bf16(v02, pf2, o0, 0, 0, 0);
      o1 = __builtin_amdgcn_mfma_f32_32x32x16_bf16(v12, pf2, o1, 0, 0, 0);
      o0 = __builtin_amdgcn_mfma_f32_32x32x16_bf16(v03, pf3, o0, 0, 0, 0);
      o1 = __builtin_amdgcn_mfma_f32_32x32x16_bf16(v13, pf3, o1, 0, 0, 0);
    }

    __syncthreads();
    cur ^= 1;
  }

  float lsum = (ls[0] + ls[1]) + (ls[2] + ls[3]);
  lsum += __shfl_xor(lsum, 32);

  const int b = bh >> 4, hd = bh & 15;
  float inv = 1.f / lsum;
  short* orow = ao + ((size_t)b * 2048 + q0 + r31) * 1024 + hd * 64;
#pragma unroll
  for (int s2 = 0; s2 < 4; ++s2) {
    s16x4 pk0, pk1;
#pragma unroll
    for (int r = 0; r < 4; ++r) {
      pk0[r] = f2bf(o0[4 * s2 + r] * inv);
      pk1[r] = f2bf(o1[4 * s2 + r] * inv);
    }
    *(s16x4*)(orow + 8 * s2 + 4 * h) = pk0;
    *(s16x4*)(orow + 32 + 8 * s2 + 4 * h) = pk1;
  }
}

// ---------------- launch ----------------
extern "C" void kernel_launch(void* const* d_in, const int* in_sizes, int n_in,
                              void* d_out, int out_size, void* d_ws, size_t ws_size,
                              hipStream_t stream) {
  const float* x = (const float*)d_in[0];
  const float* qkv_w = (const float*)d_in[1];
  const float* qkv_b = (const float*)d_in[2];
  const float* proj_w = (const float*)d_in[3];
  const float* proj_b = (const float*)d_in[4];
  float* out = (float*)d_out;

  char* ws = (char*)d_ws;
  short* xb    = (short*)(ws + 0);          // 16 MB  [8192][1024]
  short* wqkv  = (short*)(ws + 16777216);   // 6 MB   [3072][1024]
  short* wproj = (short*)(ws + 23068672);   // 2 MB   [1024][1024]
  short* qb    = (short*)(ws + 25165824);   // 16 MB  [B,H,N,Hd]
  short* kb    = (short*)(ws + 41943040);   // 16 MB  [B,H,N,Hd]
  short* vtb   = (short*)(ws + 58720256);   // 16 MB  [B,H,Hd,N] (perm'd cols)
  short* aob   = (short*)(ws + 75497472);   // 16 MB  [B,N,D]

  cvt_f32_bf16<<<8192, 256, 0, stream>>>(x, xb, 2097152);
  cvt_f32_bf16<<<3072, 256, 0, stream>>>(qkv_w, wqkv, 786432);
  cvt_f32_bf16<<<1024, 256, 0, stream>>>(proj_w, wproj, 262144);

  gemm_qkv<<<384, 512, 0, stream>>>(xb, wqkv, qkv_b, qb, kb, vtb);
  attn_kernel<<<1024, 256, 0, stream>>>(qb, kb, vtb, aob);
  gemm_bt<1><<<dim3(8, 64), 256, 0, stream>>>(aob, wproj, proj_b, 1024, out);
}

// Round 14
// 191.609 us; speedup vs baseline: 1.0538x; 1.0538x over previous
//
#include <hip/hip_runtime.h>

// MultiHeadSelfAttention: B=4, N=2048, D=1024, H=16, Hd=64
// QKV/proj: proven 128^2 2-phase gemm (exact 3.0/1.0 rounds at 2 blocks/CU).
// Attention: 64 q-rows/wave (R8 structure, grid 512 = exactly 1 round at
// 2 blocks/CU) + hardware v_exp_f32 max-free softmax + V bit2<->3 permuted
// PV fragments (no cross-lane exchange) + XCD-affinity swizzle.

typedef __attribute__((ext_vector_type(8))) short bf16x8;
typedef __attribute__((ext_vector_type(4))) short s16x4;
typedef __attribute__((ext_vector_type(4))) float f32x4;
typedef __attribute__((ext_vector_type(16))) float f32x16;
typedef __attribute__((ext_vector_type(4))) unsigned u32x4;

#define LOG2E 1.44269504088896340736f

__device__ static inline short f2bf(float f) {
  unsigned u = __builtin_bit_cast(unsigned, f);
  unsigned r = (u + 0x7fffu + ((u >> 16) & 1u)) >> 16;
  return (short)r;
}
__device__ static inline unsigned cvtpk_bf16(float lo, float hi) {
  unsigned r;
  asm("v_cvt_pk_bf16_f32 %0, %1, %2" : "=v"(r) : "v"(lo), "v"(hi));
  return r;
}
__device__ static inline float exp2_hw(float x) {
#if __has_builtin(__builtin_amdgcn_exp2f)
  return __builtin_amdgcn_exp2f(x);
#else
  float r;
  asm("v_exp_f32 %0, %1" : "=v"(r) : "v"(x));
  return r;
#endif
}

__device__ static inline void gload_lds16(const void* g, void* l) {
  __builtin_amdgcn_global_load_lds(
      (const __attribute__((address_space(1))) void*)g,
      (__attribute__((address_space(3))) void*)l, 16, 0, 0);
}

// ---------------- fp32 -> bf16 convert ----------------
__global__ void cvt_f32_bf16(const float* __restrict__ in, short* __restrict__ out, int n4) {
  int i = blockIdx.x * 256 + threadIdx.x;
  if (i < n4) {
    float4 v = ((const float4*)in)[i];
    s16x4 o4 = { f2bf(v.x), f2bf(v.y), f2bf(v.z), f2bf(v.w) };
    ((s16x4*)out)[i] = o4;
  }
}

// ---------------- GEMM C = A[M,K] * B[N,K]^T (+bias) ----------------
// EPI=0: scatter q (pre-scaled 0.125*log2e), k as [B,H,N,Hd]; v as [B,H,Hd,N]
//        with key-position bits 2,3 swapped (PV B-frag pre-permutation).
// EPI=1: fp32 out + bias.
template <int EPI>
__global__ __launch_bounds__(256, 2) void gemm_bt(
    const short* __restrict__ A, const short* __restrict__ Bm,
    const float* __restrict__ bias, int K,
    short* __restrict__ qo, short* __restrict__ ko, short* __restrict__ vto,
    float* __restrict__ outf) {
  __shared__ __align__(16) char smem[16384];
  char* As = smem;
  char* Bs = smem + 8192;
  const int tid = threadIdx.x, lane = tid & 63, w = tid >> 6;
  const int wm = w >> 1, wn = w & 1;
  const int bm = blockIdx.y, bn = blockIdx.x;

  f32x4 acc[4][4];
  const f32x4 z4 = {0.f, 0.f, 0.f, 0.f};
#pragma unroll
  for (int m = 0; m < 4; ++m)
#pragma unroll
    for (int n = 0; n < 4; ++n) acc[m][n] = z4;

  const short* Abase = A + (size_t)bm * 128 * K;
  const short* Bbase = Bm + (size_t)bn * 128 * K;

  for (int k0 = 0; k0 < K; k0 += 32) {
#pragma unroll
    for (int j = 0; j < 2; ++j) {
      int ia = w * 2 + j;
      int row = ia * 16 + (lane >> 2);
      int cl = (lane & 3) ^ (row & 3);
      gload_lds16(Abase + (size_t)row * K + k0 + cl * 8, As + ia * 1024);
      gload_lds16(Bbase + (size_t)row * K + k0 + cl * 8, Bs + ia * 1024);
    }
    __syncthreads();

    bf16x8 af[4], bf[4];
#pragma unroll
    for (int m = 0; m < 4; ++m) {
      int r = wm * 64 + m * 16 + (lane & 15);
      af[m] = *(const bf16x8*)(As + r * 64 + ((((lane >> 4)) ^ (r & 3)) << 4));
    }
#pragma unroll
    for (int n = 0; n < 4; ++n) {
      int r = wn * 64 + n * 16 + (lane & 15);
      bf[n] = *(const bf16x8*)(Bs + r * 64 + ((((lane >> 4)) ^ (r & 3)) << 4));
    }
#pragma unroll
    for (int m = 0; m < 4; ++m)
#pragma unroll
      for (int n = 0; n < 4; ++n)
        acc[m][n] = __builtin_amdgcn_mfma_f32_16x16x32_bf16(af[m], bf[n], acc[m][n], 0, 0, 0);
    __syncthreads();
  }

  if (EPI == 0) {
    const int which = bn >> 3;               // 0=q 1=k 2=v
    const int hh = ((bn & 7) << 1) | wn;     // head
    const int bidx = bm >> 4;                // batch
    const size_t bh = (size_t)bidx * 16 + hh;
#pragma unroll
    for (int nf = 0; nf < 4; ++nf) {
      int dd = nf * 16 + (lane & 15);
      float bv = bias[bn * 128 + wn * 64 + dd];
#pragma unroll
      for (int m = 0; m < 4; ++m) {
        int nr0 = (bm & 15) * 128 + wm * 64 + m * 16 + ((lane >> 4) << 2);
        if (which == 2) {
          // key-position permutation: swap bits 2,3 of key index
          int nper = (nr0 & ~12) | ((nr0 & 4) << 1) | ((nr0 & 8) >> 1);
          s16x4 pk;
#pragma unroll
          for (int r = 0; r < 4; ++r) pk[r] = f2bf(acc[m][nf][r] + bv);
          *(s16x4*)(vto + (bh * 64 + dd) * 2048 + nper) = pk;
        } else if (which == 0) {
          short* dst = qo + (bh * 2048 + nr0) * 64 + dd;
#pragma unroll
          for (int r = 0; r < 4; ++r)
            dst[(size_t)r * 64] = f2bf((acc[m][nf][r] + bv) * (0.125f * LOG2E));
        } else {
          short* dst = ko + (bh * 2048 + nr0) * 64 + dd;
#pragma unroll
          for (int r = 0; r < 4; ++r) dst[(size_t)r * 64] = f2bf(acc[m][nf][r] + bv);
        }
      }
    }
  } else {
#pragma unroll
    for (int nf = 0; nf < 4; ++nf) {
      int gn = bn * 128 + wn * 64 + nf * 16 + (lane & 15);
      float bv = bias[gn];
#pragma unroll
      for (int m = 0; m < 4; ++m) {
        int gm0 = bm * 128 + wm * 64 + m * 16 + ((lane >> 4) << 2);
        float* dst = outf + (size_t)gm0 * 1024 + gn;
#pragma unroll
        for (int r = 0; r < 4; ++r) dst[(size_t)r * 1024] = acc[m][nf][r] + bv;
      }
    }
  }
}

// pf[0..3] B-frags (K=16 each) direct from lane-owned s-values (V pre-permuted)
#define BUILD_PF(pf, sX0, sX1)                                                 \
  {                                                                            \
    u32x4 wd0 = {cvtpk_bf16(sX0[0], sX0[1]), cvtpk_bf16(sX0[2], sX0[3]),       \
                 cvtpk_bf16(sX0[4], sX0[5]), cvtpk_bf16(sX0[6], sX0[7])};      \
    pf[0] = __builtin_bit_cast(bf16x8, wd0);                                   \
    u32x4 wd1 = {cvtpk_bf16(sX0[8], sX0[9]), cvtpk_bf16(sX0[10], sX0[11]),     \
                 cvtpk_bf16(sX0[12], sX0[13]), cvtpk_bf16(sX0[14], sX0[15])};  \
    pf[1] = __builtin_bit_cast(bf16x8, wd1);                                   \
    u32x4 wd2 = {cvtpk_bf16(sX1[0], sX1[1]), cvtpk_bf16(sX1[2], sX1[3]),       \
                 cvtpk_bf16(sX1[4], sX1[5]), cvtpk_bf16(sX1[6], sX1[7])};      \
    pf[2] = __builtin_bit_cast(bf16x8, wd2);                                   \
    u32x4 wd3 = {cvtpk_bf16(sX1[8], sX1[9]), cvtpk_bf16(sX1[10], sX1[11]),     \
                 cvtpk_bf16(sX1[12], sX1[13]), cvtpk_bf16(sX1[14], sX1[15])};  \
    pf[3] = __builtin_bit_cast(bf16x8, wd3);                                   \
  }

// ---------------- flash attention, LDS-shared K/V, 64 q/wave ----------------
__global__ __launch_bounds__(256, 2) void attn_kernel(
    const short* __restrict__ q, const short* __restrict__ kk,
    const short* __restrict__ vt, short* __restrict__ ao) {
  __shared__ __align__(16) char smem[32768];  // 2 bufs x (K 8KB + V 8KB)
  const int tid = threadIdx.x, lane = tid & 63, w = tid >> 6;
  const int r31 = lane & 31, h = lane >> 5;
  const int id = blockIdx.x;
  const int xcd = id & 7, p = id >> 3;
  const int bh = xcd * 8 + (p >> 3);   // 8 bh per XCD -> K/V L2-resident
  const int qblk = p & 7;
  const int q0 = qblk * 256 + w * 64;  // wave owns q0..q0+63 (2 q-groups)

  const short* qptr = q + ((size_t)bh * 2048 + q0 + r31) * 64 + h * 8;
  const short* kgl = kk + (size_t)bh * 2048 * 64;   // [2048][64]
  const short* vgl = vt + (size_t)bh * 64 * 2048;   // V^T [64][2048] (perm'd cols)

  // staging: thread stages rows srow, srow+8; source col pre-swizzled so LDS
  // image is [row][col ^ ((row&7)<<4)].
  const int srow = w * 16 + (lane >> 3);
  const int scol = ((lane & 7) * 8) ^ ((lane >> 3) << 3);  // shorts
  const int ldst = w * 2048;                               // bytes, +j*1024

  // Q fragments for both q-groups (pre-scaled by 0.125*log2e)
  bf16x8 qfA[4], qfB[4];
#pragma unroll
  for (int dk = 0; dk < 4; ++dk) {
    qfA[dk] = *(const bf16x8*)(qptr + dk * 16);
    qfB[dk] = *(const bf16x8*)(qptr + 32 * 64 + dk * 16);
  }

  f32x16 oA0, oA1, oB0, oB1;
#pragma unroll
  for (int e = 0; e < 16; ++e) { oA0[e] = 0.f; oA1[e] = 0.f; oB0[e] = 0.f; oB1[e] = 0.f; }
  float lsA[8], lsB[8];
#pragma unroll
  for (int e = 0; e < 8; ++e) { lsA[e] = 0.f; lsB[e] = 0.f; }

  // prologue: stage tile 0 into buf 0
#pragma unroll
  for (int j = 0; j < 2; ++j) {
    gload_lds16(kgl + (size_t)(srow + j * 8) * 64 + scol, smem + ldst + j * 1024);
    gload_lds16(vgl + (size_t)(srow + j * 8) * 2048 + scol, smem + 8192 + ldst + j * 1024);
  }
  __syncthreads();

  int cur = 0;
  for (int t = 0; t < 2048; t += 64) {
    const char* Kb = smem + cur * 16384;
    const char* Vb = smem + cur * 16384 + 8192;

    // ---- prefetch next tile into other buffer ----
    if (t + 64 < 2048) {
      char* nb = (char*)smem + (cur ^ 1) * 16384;
#pragma unroll
      for (int j = 0; j < 2; ++j) {
        gload_lds16(kgl + (size_t)(t + 64 + srow + j * 8) * 64 + scol, nb + ldst + j * 1024);
        gload_lds16(vgl + (size_t)(srow + j * 8) * 2048 + (t + 64) + scol, nb + 8192 + ldst + j * 1024);
      }
    }

    // ---- K fragments from LDS (swizzled, conflict-free) ----
    bf16x8 kf0[4], kf1[4];
#pragma unroll
    for (int dk = 0; dk < 4; ++dk) {
      int cb = (dk * 32 + h * 16) ^ ((r31 & 7) << 4);
      kf0[dk] = *(const bf16x8*)(Kb + r31 * 128 + cb);
      kf1[dk] = *(const bf16x8*)(Kb + (32 + r31) * 128 + cb);
    }

    // ---- QK^T for both q-groups (kf shared) ----
    f32x16 sA0, sA1, sB0, sB1;
#pragma unroll
    for (int e = 0; e < 16; ++e) { sA0[e] = 0.f; sA1[e] = 0.f; sB0[e] = 0.f; sB1[e] = 0.f; }
#pragma unroll
    for (int dk = 0; dk < 4; ++dk) {
      sA0 = __builtin_amdgcn_mfma_f32_32x32x16_bf16(kf0[dk], qfA[dk], sA0, 0, 0, 0);
      sA1 = __builtin_amdgcn_mfma_f32_32x32x16_bf16(kf1[dk], qfA[dk], sA1, 0, 0, 0);
      sB0 = __builtin_amdgcn_mfma_f32_32x32x16_bf16(kf0[dk], qfB[dk], sB0, 0, 0, 0);
      sB1 = __builtin_amdgcn_mfma_f32_32x32x16_bf16(kf1[dk], qfB[dk], sB1, 0, 0, 0);
    }

    // ---- V^T fragments from LDS ----
    bf16x8 vf[8];
#pragma unroll
    for (int db = 0; db < 2; ++db)
#pragma unroll
      for (int ks = 0; ks < 4; ++ks) {
        int cb = (ks * 32 + h * 16) ^ ((r31 & 7) << 4);
        vf[db * 4 + ks] = *(const bf16x8*)(Vb + (db * 32 + r31) * 128 + cb);
      }

    // ---- max-free softmax: P = exp2(s) via v_exp_f32; l partials ----
#pragma unroll
    for (int e = 0; e < 16; ++e) {
      sA0[e] = exp2_hw(sA0[e]);
      sA1[e] = exp2_hw(sA1[e]);
      sB0[e] = exp2_hw(sB0[e]);
      sB1[e] = exp2_hw(sB1[e]);
    }
#pragma unroll
    for (int e = 0; e < 8; ++e) {
      lsA[e] += (sA0[e] + sA0[e + 8]) + (sA1[e] + sA1[e + 8]);
      lsB[e] += (sB0[e] + sB0[e + 8]) + (sB1[e] + sB1[e + 8]);
    }

    // ---- P^T B-frags: direct cvt_pk (V pre-permuted; no exchange) ----
    bf16x8 pfA[4], pfB[4];
    BUILD_PF(pfA, sA0, sA1);
    BUILD_PF(pfB, sB0, sB1);

    // ---- O^T += V^T . P^T ----
#pragma unroll
    for (int ks = 0; ks < 4; ++ks) {
      oA0 = __builtin_amdgcn_mfma_f32_32x32x16_bf16(vf[ks], pfA[ks], oA0, 0, 0, 0);
      oA1 = __builtin_amdgcn_mfma_f32_32x32x16_bf16(vf[4 + ks], pfA[ks], oA1, 0, 0, 0);
      oB0 = __builtin_amdgcn_mfma_f32_32x32x16_bf16(vf[ks], pfB[ks], oB0, 0, 0, 0);
      oB1 = __builtin_amdgcn_mfma_f32_32x32x16_bf16(vf[4 + ks], pfB[ks], oB1, 0, 0, 0);
    }

    __syncthreads();
    cur ^= 1;
  }

  // ---- epilogue: l trees + O/l -> ao bf16 [B,N,D] ----
  const int b = bh >> 4, hd = bh & 15;
#pragma unroll
  for (int st = 4; st >= 1; st >>= 1)
#pragma unroll
    for (int e = 0; e < 4; ++e)
      if (e < st) { lsA[e] += lsA[e + st]; lsB[e] += lsB[e + st]; }
  float lsumA = lsA[0] + __shfl_xor(lsA[0], 32);
  float lsumB = lsB[0] + __shfl_xor(lsB[0], 32);
  float invA = 1.f / lsumA, invB = 1.f / lsumB;

  short* orowA = ao + ((size_t)b * 2048 + q0 + r31) * 1024 + hd * 64;
  short* orowB = orowA + (size_t)32 * 1024;
#pragma unroll
  for (int s2 = 0; s2 < 4; ++s2) {
    s16x4 a0, a1, b0, b1;
#pragma unroll
    for (int r = 0; r < 4; ++r) {
      a0[r] = f2bf(oA0[4 * s2 + r] * invA);   // d = 8*s2 + 4*h + r
      a1[r] = f2bf(oA1[4 * s2 + r] * invA);   // d+32
      b0[r] = f2bf(oB0[4 * s2 + r] * invB);
      b1[r] = f2bf(oB1[4 * s2 + r] * invB);
    }
    *(s16x4*)(orowA + 8 * s2 + 4 * h) = a0;
    *(s16x4*)(orowA + 32 + 8 * s2 + 4 * h) = a1;
    *(s16x4*)(orowB + 8 * s2 + 4 * h) = b0;
    *(s16x4*)(orowB + 32 + 8 * s2 + 4 * h) = b1;
  }
}

// ---------------- launch ----------------
extern "C" void kernel_launch(void* const* d_in, const int* in_sizes, int n_in,
                              void* d_out, int out_size, void* d_ws, size_t ws_size,
                              hipStream_t stream) {
  const float* x = (const float*)d_in[0];
  const float* qkv_w = (const float*)d_in[1];
  const float* qkv_b = (const float*)d_in[2];
  const float* proj_w = (const float*)d_in[3];
  const float* proj_b = (const float*)d_in[4];
  float* out = (float*)d_out;

  char* ws = (char*)d_ws;
  short* xb    = (short*)(ws + 0);          // 16 MB  [8192][1024]
  short* wqkv  = (short*)(ws + 16777216);   // 6 MB   [3072][1024]
  short* wproj = (short*)(ws + 23068672);   // 2 MB   [1024][1024]
  short* qb    = (short*)(ws + 25165824);   // 16 MB  [B,H,N,Hd]
  short* kb    = (short*)(ws + 41943040);   // 16 MB  [B,H,N,Hd]
  short* vtb   = (short*)(ws + 58720256);   // 16 MB  [B,H,Hd,N] (perm'd cols)
  short* aob   = (short*)(ws + 75497472);   // 16 MB  [B,N,D]

  cvt_f32_bf16<<<8192, 256, 0, stream>>>(x, xb, 2097152);
  cvt_f32_bf16<<<3072, 256, 0, stream>>>(qkv_w, wqkv, 786432);
  cvt_f32_bf16<<<1024, 256, 0, stream>>>(proj_w, wproj, 262144);

  gemm_bt<0><<<dim3(24, 64), 256, 0, stream>>>(xb, wqkv, qkv_b, 1024, qb, kb, vtb, nullptr);
  attn_kernel<<<512, 256, 0, stream>>>(qb, kb, vtb, aob);
  gemm_bt<1><<<dim3(8, 64), 256, 0, stream>>>(aob, wproj, proj_b, 1024, nullptr, nullptr, nullptr, out);
}

// Round 15
// 185.436 us; speedup vs baseline: 1.0889x; 1.0333x over previous
//
#include <hip/hip_runtime.h>

// MultiHeadSelfAttention: B=4, N=2048, D=1024, H=16, Hd=64
// GEMMs (QKV + proj): 128^2 tile, BK=32, now DOUBLE-BUFFERED with one
// barrier/iter (prefetch k+1 before consuming k -- the attn-proven pattern)
// and a full-rank LDS swizzle swz(r)=(r&3)^((r>>2)&3) (kills the 4-way
// ds_read bank conflict of the old (r&3)-only swizzle).
// Attention: 64 q-rows/wave, LDS-shared K/V, max-free softmax (hw v_exp_f32),
// V bit2<->3 permuted PV fragments, XCD-affinity swizzle (R14, unchanged).

typedef __attribute__((ext_vector_type(8))) short bf16x8;
typedef __attribute__((ext_vector_type(4))) short s16x4;
typedef __attribute__((ext_vector_type(4))) float f32x4;
typedef __attribute__((ext_vector_type(16))) float f32x16;
typedef __attribute__((ext_vector_type(4))) unsigned u32x4;

#define LOG2E 1.44269504088896340736f

__device__ static inline short f2bf(float f) {
  unsigned u = __builtin_bit_cast(unsigned, f);
  unsigned r = (u + 0x7fffu + ((u >> 16) & 1u)) >> 16;
  return (short)r;
}
__device__ static inline unsigned cvtpk_bf16(float lo, float hi) {
  unsigned r;
  asm("v_cvt_pk_bf16_f32 %0, %1, %2" : "=v"(r) : "v"(lo), "v"(hi));
  return r;
}
__device__ static inline float exp2_hw(float x) {
#if __has_builtin(__builtin_amdgcn_exp2f)
  return __builtin_amdgcn_exp2f(x);
#else
  float r;
  asm("v_exp_f32 %0, %1" : "=v"(r) : "v"(x));
  return r;
#endif
}

__device__ static inline void gload_lds16(const void* g, void* l) {
  __builtin_amdgcn_global_load_lds(
      (const __attribute__((address_space(1))) void*)g,
      (__attribute__((address_space(3))) void*)l, 16, 0, 0);
}

// ---------------- fp32 -> bf16 convert ----------------
__global__ void cvt_f32_bf16(const float* __restrict__ in, short* __restrict__ out, int n4) {
  int i = blockIdx.x * 256 + threadIdx.x;
  if (i < n4) {
    float4 v = ((const float4*)in)[i];
    s16x4 o4 = { f2bf(v.x), f2bf(v.y), f2bf(v.z), f2bf(v.w) };
    ((s16x4*)out)[i] = o4;
  }
}

// ---------------- GEMM C = A[M,K] * B[N,K]^T (+bias) ----------------
// Double-buffered, 1 barrier/iter. LDS image: row r (64B) holds logical
// 16B-chunk k at physical chunk k ^ swz(r), swz(r) = (r&3)^((r>>2)&3).
// EPI=0: scatter q (pre-scaled 0.125*log2e), k as [B,H,N,Hd]; v as [B,H,Hd,N]
//        with key-position bits 2,3 swapped (PV B-frag pre-permutation).
// EPI=1: fp32 out + bias.
template <int EPI>
__global__ __launch_bounds__(256, 2) void gemm_bt(
    const short* __restrict__ A, const short* __restrict__ Bm,
    const float* __restrict__ bias, int K,
    short* __restrict__ qo, short* __restrict__ ko, short* __restrict__ vto,
    float* __restrict__ outf) {
  __shared__ __align__(16) char smem[32768];  // 2 bufs x (As 8KB + Bs 8KB)
  const int tid = threadIdx.x, lane = tid & 63, w = tid >> 6;
  const int wm = w >> 1, wn = w & 1;
  const int bm = blockIdx.y, bn = blockIdx.x;

  f32x4 acc[4][4];
  const f32x4 z4 = {0.f, 0.f, 0.f, 0.f};
#pragma unroll
  for (int m = 0; m < 4; ++m)
#pragma unroll
    for (int n = 0; n < 4; ++n) acc[m][n] = z4;

  const short* Abase = A + (size_t)bm * 128 * K;
  const short* Bbase = Bm + (size_t)bn * 128 * K;

  // stage tile at k0 into buffer buf; source col pre-inverse-swizzled so the
  // linear LDS dest (wave base + lane*16) lands the swizzled image.
  const int cl = (lane & 3) ^ ((lane >> 2) & 3) ^ (lane >> 4);  // = (lane&3)^swz(row)
  auto STAGE = [&](int k0, int buf) {
    char* As_ = smem + buf * 16384;
    char* Bs_ = As_ + 8192;
#pragma unroll
    for (int j = 0; j < 2; ++j) {
      int ia = w * 2 + j;
      int row = ia * 16 + (lane >> 2);
      gload_lds16(Abase + (size_t)row * K + k0 + cl * 8, As_ + ia * 1024);
      gload_lds16(Bbase + (size_t)row * K + k0 + cl * 8, Bs_ + ia * 1024);
    }
  };

  STAGE(0, 0);
  __syncthreads();

  int cur = 0;
  for (int k0 = 0; k0 < K; k0 += 32) {
    if (k0 + 32 < K) STAGE(k0 + 32, cur ^ 1);

    const char* As_ = smem + cur * 16384;
    const char* Bs_ = As_ + 8192;
    bf16x8 af[4], bf[4];
#pragma unroll
    for (int m = 0; m < 4; ++m) {
      int r = wm * 64 + m * 16 + (lane & 15);
      af[m] = *(const bf16x8*)(As_ + r * 64 +
                               (((lane >> 4) ^ (r & 3) ^ ((r >> 2) & 3)) << 4));
    }
#pragma unroll
    for (int n = 0; n < 4; ++n) {
      int r = wn * 64 + n * 16 + (lane & 15);
      bf[n] = *(const bf16x8*)(Bs_ + r * 64 +
                               (((lane >> 4) ^ (r & 3) ^ ((r >> 2) & 3)) << 4));
    }
#pragma unroll
    for (int m = 0; m < 4; ++m)
#pragma unroll
      for (int n = 0; n < 4; ++n)
        acc[m][n] = __builtin_amdgcn_mfma_f32_16x16x32_bf16(af[m], bf[n], acc[m][n], 0, 0, 0);

    __syncthreads();   // drains prefetch (issued ~1000 cyc ago) + read fence
    cur ^= 1;
  }

  if (EPI == 0) {
    const int which = bn >> 3;               // 0=q 1=k 2=v
    const int hh = ((bn & 7) << 1) | wn;     // head
    const int bidx = bm >> 4;                // batch
    const size_t bh = (size_t)bidx * 16 + hh;
#pragma unroll
    for (int nf = 0; nf < 4; ++nf) {
      int dd = nf * 16 + (lane & 15);
      float bv = bias[bn * 128 + wn * 64 + dd];
#pragma unroll
      for (int m = 0; m < 4; ++m) {
        int nr0 = (bm & 15) * 128 + wm * 64 + m * 16 + ((lane >> 4) << 2);
        if (which == 2) {
          // key-position permutation: swap bits 2,3 of key index
          int nper = (nr0 & ~12) | ((nr0 & 4) << 1) | ((nr0 & 8) >> 1);
          s16x4 pk;
#pragma unroll
          for (int r = 0; r < 4; ++r) pk[r] = f2bf(acc[m][nf][r] + bv);
          *(s16x4*)(vto + (bh * 64 + dd) * 2048 + nper) = pk;
        } else if (which == 0) {
          short* dst = qo + (bh * 2048 + nr0) * 64 + dd;
#pragma unroll
          for (int r = 0; r < 4; ++r)
            dst[(size_t)r * 64] = f2bf((acc[m][nf][r] + bv) * (0.125f * LOG2E));
        } else {
          short* dst = ko + (bh * 2048 + nr0) * 64 + dd;
#pragma unroll
          for (int r = 0; r < 4; ++r) dst[(size_t)r * 64] = f2bf(acc[m][nf][r] + bv);
        }
      }
    }
  } else {
#pragma unroll
    for (int nf = 0; nf < 4; ++nf) {
      int gn = bn * 128 + wn * 64 + nf * 16 + (lane & 15);
      float bv = bias[gn];
#pragma unroll
      for (int m = 0; m < 4; ++m) {
        int gm0 = bm * 128 + wm * 64 + m * 16 + ((lane >> 4) << 2);
        float* dst = outf + (size_t)gm0 * 1024 + gn;
#pragma unroll
        for (int r = 0; r < 4; ++r) dst[(size_t)r * 1024] = acc[m][nf][r] + bv;
      }
    }
  }
}

// pf[0..3] B-frags (K=16 each) direct from lane-owned s-values (V pre-permuted)
#define BUILD_PF(pf, sX0, sX1)                                                 \
  {                                                                            \
    u32x4 wd0 = {cvtpk_bf16(sX0[0], sX0[1]), cvtpk_bf16(sX0[2], sX0[3]),       \
                 cvtpk_bf16(sX0[4], sX0[5]), cvtpk_bf16(sX0[6], sX0[7])};      \
    pf[0] = __builtin_bit_cast(bf16x8, wd0);                                   \
    u32x4 wd1 = {cvtpk_bf16(sX0[8], sX0[9]), cvtpk_bf16(sX0[10], sX0[11]),     \
                 cvtpk_bf16(sX0[12], sX0[13]), cvtpk_bf16(sX0[14], sX0[15])};  \
    pf[1] = __builtin_bit_cast(bf16x8, wd1);                                   \
    u32x4 wd2 = {cvtpk_bf16(sX1[0], sX1[1]), cvtpk_bf16(sX1[2], sX1[3]),       \
                 cvtpk_bf16(sX1[4], sX1[5]), cvtpk_bf16(sX1[6], sX1[7])};      \
    pf[2] = __builtin_bit_cast(bf16x8, wd2);                                   \
    u32x4 wd3 = {cvtpk_bf16(sX1[8], sX1[9]), cvtpk_bf16(sX1[10], sX1[11]),     \
                 cvtpk_bf16(sX1[12], sX1[13]), cvtpk_bf16(sX1[14], sX1[15])};  \
    pf[3] = __builtin_bit_cast(bf16x8, wd3);                                   \
  }

// ---------------- flash attention, LDS-shared K/V, 64 q/wave ----------------
__global__ __launch_bounds__(256, 2) void attn_kernel(
    const short* __restrict__ q, const short* __restrict__ kk,
    const short* __restrict__ vt, short* __restrict__ ao) {
  __shared__ __align__(16) char smem[32768];  // 2 bufs x (K 8KB + V 8KB)
  const int tid = threadIdx.x, lane = tid & 63, w = tid >> 6;
  const int r31 = lane & 31, h = lane >> 5;
  const int id = blockIdx.x;
  const int xcd = id & 7, p = id >> 3;
  const int bh = xcd * 8 + (p >> 3);   // 8 bh per XCD -> K/V L2-resident
  const int qblk = p & 7;
  const int q0 = qblk * 256 + w * 64;  // wave owns q0..q0+63 (2 q-groups)

  const short* qptr = q + ((size_t)bh * 2048 + q0 + r31) * 64 + h * 8;
  const short* kgl = kk + (size_t)bh * 2048 * 64;   // [2048][64]
  const short* vgl = vt + (size_t)bh * 64 * 2048;   // V^T [64][2048] (perm'd cols)

  // staging: thread stages rows srow, srow+8; source col pre-swizzled so LDS
  // image is [row][col ^ ((row&7)<<4)].
  const int srow = w * 16 + (lane >> 3);
  const int scol = ((lane & 7) * 8) ^ ((lane >> 3) << 3);  // shorts
  const int ldst = w * 2048;                               // bytes, +j*1024

  // Q fragments for both q-groups (pre-scaled by 0.125*log2e)
  bf16x8 qfA[4], qfB[4];
#pragma unroll
  for (int dk = 0; dk < 4; ++dk) {
    qfA[dk] = *(const bf16x8*)(qptr + dk * 16);
    qfB[dk] = *(const bf16x8*)(qptr + 32 * 64 + dk * 16);
  }

  f32x16 oA0, oA1, oB0, oB1;
#pragma unroll
  for (int e = 0; e < 16; ++e) { oA0[e] = 0.f; oA1[e] = 0.f; oB0[e] = 0.f; oB1[e] = 0.f; }
  float lsA[8], lsB[8];
#pragma unroll
  for (int e = 0; e < 8; ++e) { lsA[e] = 0.f; lsB[e] = 0.f; }

  // prologue: stage tile 0 into buf 0
#pragma unroll
  for (int j = 0; j < 2; ++j) {
    gload_lds16(kgl + (size_t)(srow + j * 8) * 64 + scol, smem + ldst + j * 1024);
    gload_lds16(vgl + (size_t)(srow + j * 8) * 2048 + scol, smem + 8192 + ldst + j * 1024);
  }
  __syncthreads();

  int cur = 0;
  for (int t = 0; t < 2048; t += 64) {
    const char* Kb = smem + cur * 16384;
    const char* Vb = smem + cur * 16384 + 8192;

    // ---- prefetch next tile into other buffer ----
    if (t + 64 < 2048) {
      char* nb = (char*)smem + (cur ^ 1) * 16384;
#pragma unroll
      for (int j = 0; j < 2; ++j) {
        gload_lds16(kgl + (size_t)(t + 64 + srow + j * 8) * 64 + scol, nb + ldst + j * 1024);
        gload_lds16(vgl + (size_t)(srow + j * 8) * 2048 + (t + 64) + scol, nb + 8192 + ldst + j * 1024);
      }
    }

    // ---- K fragments from LDS (swizzled, conflict-free) ----
    bf16x8 kf0[4], kf1[4];
#pragma unroll
    for (int dk = 0; dk < 4; ++dk) {
      int cb = (dk * 32 + h * 16) ^ ((r31 & 7) << 4);
      kf0[dk] = *(const bf16x8*)(Kb + r31 * 128 + cb);
      kf1[dk] = *(const bf16x8*)(Kb + (32 + r31) * 128 + cb);
    }

    // ---- QK^T for both q-groups (kf shared) ----
    f32x16 sA0, sA1, sB0, sB1;
#pragma unroll
    for (int e = 0; e < 16; ++e) { sA0[e] = 0.f; sA1[e] = 0.f; sB0[e] = 0.f; sB1[e] = 0.f; }
#pragma unroll
    for (int dk = 0; dk < 4; ++dk) {
      sA0 = __builtin_amdgcn_mfma_f32_32x32x16_bf16(kf0[dk], qfA[dk], sA0, 0, 0, 0);
      sA1 = __builtin_amdgcn_mfma_f32_32x32x16_bf16(kf1[dk], qfA[dk], sA1, 0, 0, 0);
      sB0 = __builtin_amdgcn_mfma_f32_32x32x16_bf16(kf0[dk], qfB[dk], sB0, 0, 0, 0);
      sB1 = __builtin_amdgcn_mfma_f32_32x32x16_bf16(kf1[dk], qfB[dk], sB1, 0, 0, 0);
    }

    // ---- V^T fragments from LDS ----
    bf16x8 vf[8];
#pragma unroll
    for (int db = 0; db < 2; ++db)
#pragma unroll
      for (int ks = 0; ks < 4; ++ks) {
        int cb = (ks * 32 + h * 16) ^ ((r31 & 7) << 4);
        vf[db * 4 + ks] = *(const bf16x8*)(Vb + (db * 32 + r31) * 128 + cb);
      }

    // ---- max-free softmax: P = exp2(s) via v_exp_f32; l partials ----
#pragma unroll
    for (int e = 0; e < 16; ++e) {
      sA0[e] = exp2_hw(sA0[e]);
      sA1[e] = exp2_hw(sA1[e]);
      sB0[e] = exp2_hw(sB0[e]);
      sB1[e] = exp2_hw(sB1[e]);
    }
#pragma unroll
    for (int e = 0; e < 8; ++e) {
      lsA[e] += (sA0[e] + sA0[e + 8]) + (sA1[e] + sA1[e + 8]);
      lsB[e] += (sB0[e] + sB0[e + 8]) + (sB1[e] + sB1[e + 8]);
    }

    // ---- P^T B-frags: direct cvt_pk (V pre-permuted; no exchange) ----
    bf16x8 pfA[4], pfB[4];
    BUILD_PF(pfA, sA0, sA1);
    BUILD_PF(pfB, sB0, sB1);

    // ---- O^T += V^T . P^T ----
#pragma unroll
    for (int ks = 0; ks < 4; ++ks) {
      oA0 = __builtin_amdgcn_mfma_f32_32x32x16_bf16(vf[ks], pfA[ks], oA0, 0, 0, 0);
      oA1 = __builtin_amdgcn_mfma_f32_32x32x16_bf16(vf[4 + ks], pfA[ks], oA1, 0, 0, 0);
      oB0 = __builtin_amdgcn_mfma_f32_32x32x16_bf16(vf[ks], pfB[ks], oB0, 0, 0, 0);
      oB1 = __builtin_amdgcn_mfma_f32_32x32x16_bf16(vf[4 + ks], pfB[ks], oB1, 0, 0, 0);
    }

    __syncthreads();
    cur ^= 1;
  }

  // ---- epilogue: l trees + O/l -> ao bf16 [B,N,D] ----
  const int b = bh >> 4, hd = bh & 15;
#pragma unroll
  for (int st = 4; st >= 1; st >>= 1)
#pragma unroll
    for (int e = 0; e < 4; ++e)
      if (e < st) { lsA[e] += lsA[e + st]; lsB[e] += lsB[e + st]; }
  float lsumA = lsA[0] + __shfl_xor(lsA[0], 32);
  float lsumB = lsB[0] + __shfl_xor(lsB[0], 32);
  float invA = 1.f / lsumA, invB = 1.f / lsumB;

  short* orowA = ao + ((size_t)b * 2048 + q0 + r31) * 1024 + hd * 64;
  short* orowB = orowA + (size_t)32 * 1024;
#pragma unroll
  for (int s2 = 0; s2 < 4; ++s2) {
    s16x4 a0, a1, b0, b1;
#pragma unroll
    for (int r = 0; r < 4; ++r) {
      a0[r] = f2bf(oA0[4 * s2 + r] * invA);   // d = 8*s2 + 4*h + r
      a1[r] = f2bf(oA1[4 * s2 + r] * invA);   // d+32
      b0[r] = f2bf(oB0[4 * s2 + r] * invB);
      b1[r] = f2bf(oB1[4 * s2 + r] * invB);
    }
    *(s16x4*)(orowA + 8 * s2 + 4 * h) = a0;
    *(s16x4*)(orowA + 32 + 8 * s2 + 4 * h) = a1;
    *(s16x4*)(orowB + 8 * s2 + 4 * h) = b0;
    *(s16x4*)(orowB + 32 + 8 * s2 + 4 * h) = b1;
  }
}

// ---------------- launch ----------------
extern "C" void kernel_launch(void* const* d_in, const int* in_sizes, int n_in,
                              void* d_out, int out_size, void* d_ws, size_t ws_size,
                              hipStream_t stream) {
  const float* x = (const float*)d_in[0];
  const float* qkv_w = (const float*)d_in[1];
  const float* qkv_b = (const float*)d_in[2];
  const float* proj_w = (const float*)d_in[3];
  const float* proj_b = (const float*)d_in[4];
  float* out = (float*)d_out;

  char* ws = (char*)d_ws;
  short* xb    = (short*)(ws + 0);          // 16 MB  [8192][1024]
  short* wqkv  = (short*)(ws + 16777216);   // 6 MB   [3072][1024]
  short* wproj = (short*)(ws + 23068672);   // 2 MB   [1024][1024]
  short* qb    = (short*)(ws + 25165824);   // 16 MB  [B,H,N,Hd]
  short* kb    = (short*)(ws + 41943040);   // 16 MB  [B,H,N,Hd]
  short* vtb   = (short*)(ws + 58720256);   // 16 MB  [B,H,Hd,N] (perm'd cols)
  short* aob   = (short*)(ws + 75497472);   // 16 MB  [B,N,D]

  cvt_f32_bf16<<<8192, 256, 0, stream>>>(x, xb, 2097152);
  cvt_f32_bf16<<<3072, 256, 0, stream>>>(qkv_w, wqkv, 786432);
  cvt_f32_bf16<<<1024, 256, 0, stream>>>(proj_w, wproj, 262144);

  gemm_bt<0><<<dim3(24, 64), 256, 0, stream>>>(xb, wqkv, qkv_b, 1024, qb, kb, vtb, nullptr);
  attn_kernel<<<512, 256, 0, stream>>>(qb, kb, vtb, aob);
  gemm_bt<1><<<dim3(8, 64), 256, 0, stream>>>(aob, wproj, proj_b, 1024, nullptr, nullptr, nullptr, out);
}